// Round 1
// baseline (314.586 us; speedup 1.0000x reference)
//
#include <hip/hip_runtime.h>
#include <hip/hip_bf16.h>
#include <stdint.h>

// Problem constants (reference: N=500000, F_IN=10, HID=32, OUT=2, d_in=42)
// Settled world model (R0-R4 evidence):
//   ALL float tensors (x, h, weights, biases, outputs) are f32 on device.
//   The harness compares against a bf16-QUANTIZED np reference with a
//   bf16-floor threshold (0.088) — hence the "(bf16, ref=np)" label.
//   Outputs flat f32: out [N,2] at [0,1e6), h_new [N,32] at [1e6,17e6).
// Input dtype auto-detection retained (proven to resolve f32; guards drift).
//
// R5 change (register-pressure fix):
//   Old structure kept xh[42]+z[32]+rh[32]+hnv[32] (~138 floats) live across
//   phase 2 under a 64-VGPR allocation -> ~70 floats/thread spilled to
//   scratch (VALUBusy 49% at 37% occupancy, 126us dispatch vs ~26us FMA
//   floor). New structure:
//     Phase A: rh[32] only (r-gate).
//     Phase B: per-j compute z_j, h~_j, blend, head-accumulate; z consumed
//              immediately; h_new stored in float4 chunks every 4 j.
//   Peak live set ~84 floats; __launch_bounds__(256,4) caps VGPR at 128
//   (4 waves/SIMD = 50% occupancy) with zero spills.
static constexpr int N_NODES = 500000;
static constexpr int DIN     = 42;    // F_IN + HID
static constexpr int HIDF    = 32;

// d_ws float layout (written by prep_kernel every launch):
//   [0)      Wz_t[32][42]  (combined W_z[0]+W_z[1], transposed to [j][k])
//   [1344)   Wr_t[32][42]
//   [2688)   Wh_t[32][42]
//   [4032)   bz[32]  [4064) br[32]  [4096) bh[32]
//   [4128)   Wlin[2][32]  [4192) blin[2]
//   [4200)   x_is_f32 flag   [4201) h_is_f32 flag

__device__ __forceinline__ float bfdec(uint32_t b){
  union{uint32_t u; float f;} c; c.u = b << 16; return c.f;
}
__device__ __forceinline__ float bf_lo(uint32_t u){ union{uint32_t u; float f;} c; c.u = u << 16; return c.f; }
__device__ __forceinline__ float bf_hi(uint32_t u){ union{uint32_t u; float f;} c; c.u = u & 0xffff0000u; return c.f; }
__device__ __forceinline__ float sigmoid_fast(float x){
  float e = __expf(-x);
  return __builtin_amdgcn_rcpf(1.0f + e);
}
__device__ __forceinline__ float tanh_fast(float x){
  float e = __expf(2.0f * x);
  return 1.0f - 2.0f * __builtin_amdgcn_rcpf(e + 1.0f);
}

// bf16-packed data: lo u16 of each u32 decodes to a real value (|v| <~ 6).
// f32 data: lo u16 = random mantissa bits -> decoded bf16 exponent uniform
// 0..255 -> max over K samples explodes past 1e6 w.p. ~1.
__device__ bool detect_f32_words(const uint32_t* w, int K){
  float m = 0.0f;
  for (int i = 0; i < K; i++) m = fmaxf(m, fabsf(bfdec(w[i] & 0xffffu)));
  return !(m < 1e6f);   // NaN-safe: NaN => f32
}
__device__ __forceinline__ float wload(const void* p, int idx, bool f32w){
  if (f32w) return ((const float*)p)[idx];
  return bfdec(((const uint16_t*)p)[idx]);
}

__global__ void prep_kernel(const void* __restrict__ Wz,
                            const void* __restrict__ bz,
                            const void* __restrict__ Wr,
                            const void* __restrict__ br,
                            const void* __restrict__ Wh,
                            const void* __restrict__ bh,
                            const void* __restrict__ Wl,
                            const void* __restrict__ bl,
                            const uint32_t* __restrict__ xg,
                            const uint32_t* __restrict__ hg,
                            float* __restrict__ ws)
{
  const bool f32w = detect_f32_words((const uint32_t*)Wz, 64);
  int i = blockIdx.x * 256 + threadIdx.x;
  if (i < 1344) {
    // transpose + combine: Wt[j*42+k] = W[0][k][j] + W[1][k][j]
    int j = i / DIN;
    int k = i - j * DIN;
    int src = k * HIDF + j;
    ws[i]        = wload(Wz, src, f32w) + wload(Wz, 1344 + src, f32w);
    ws[1344 + i] = wload(Wr, src, f32w) + wload(Wr, 1344 + src, f32w);
    ws[2688 + i] = wload(Wh, src, f32w) + wload(Wh, 1344 + src, f32w);
  } else if (i < 1506) {
    int r = i - 1344;
    if      (r < 32)  ws[4032 + r]       = wload(bz, r,       f32w);
    else if (r < 64)  ws[4064 + (r-32)]  = wload(br, r-32,    f32w);
    else if (r < 96)  ws[4096 + (r-64)]  = wload(bh, r-64,    f32w);
    else if (r < 160) ws[4128 + (r-96)]  = wload(Wl, r-96,    f32w);
    else              ws[4192 + (r-160)] = wload(bl, r-160,   f32w);
  } else if (i == 1520) {
    ws[4200] = detect_f32_words(xg, 256) ? 1.0f : 0.0f;
  } else if (i == 1521) {
    ws[4201] = detect_f32_words(hg, 256) ? 1.0f : 0.0f;
  }
}

__global__ __launch_bounds__(256, 4) void dcrnn_kernel(
    const uint32_t* __restrict__ xg,    // x [N,10]: f32 (10 words/row) or bf16 (5 u32/row)
    const uint32_t* __restrict__ hg,    // h [N,32]: f32 (32 words/row) or bf16 (16 u32/row)
    const float*    __restrict__ ws,
    float* __restrict__ out0,           // f32 [N,2]   (d_out f32 offset 0)
    float* __restrict__ outh)           // f32 [N,32]  (d_out f32 offset 2N)
{
  const int n = blockIdx.x * 256 + threadIdx.x;
  if (n >= N_NODES) return;

  const float* Wz = ws;
  const float* Wr = ws + 1344;
  const float* Wh = ws + 2688;
  const float* bz = ws + 4032;
  const float* br = ws + 4064;
  const float* bh = ws + 4096;
  const float* Wl = ws + 4128;
  const float* bl = ws + 4192;
  const bool x_f32 = ws[4200] != 0.0f;   // wave-uniform scalar branch
  const bool h_f32 = ws[4201] != 0.0f;

  // xh = concat(x, h) in registers, f32
  float xh[DIN];
  if (x_f32) {
    const float2* xr = (const float2*)((const float*)xg + (size_t)n * 10);
    #pragma unroll
    for (int i = 0; i < 5; i++){ float2 v = xr[i]; xh[2*i] = v.x; xh[2*i+1] = v.y; }
  } else {
    const uint32_t* xr = xg + (size_t)n * 5;
    #pragma unroll
    for (int i = 0; i < 5; i++){ uint32_t u = xr[i]; xh[2*i] = bf_lo(u); xh[2*i+1] = bf_hi(u); }
  }
  if (h_f32) {
    const float4* hr = (const float4*)((const float*)hg + (size_t)n * 32);
    #pragma unroll
    for (int i = 0; i < 8; i++){
      float4 v = hr[i];
      xh[10+4*i] = v.x; xh[10+4*i+1] = v.y; xh[10+4*i+2] = v.z; xh[10+4*i+3] = v.w;
    }
  } else {
    const uint4* hr = (const uint4*)(hg + (size_t)n * 16);
    #pragma unroll
    for (int i = 0; i < 4; i++){
      uint4 v = hr[i];
      xh[10+8*i]   = bf_lo(v.x); xh[10+8*i+1] = bf_hi(v.x);
      xh[10+8*i+2] = bf_lo(v.y); xh[10+8*i+3] = bf_hi(v.y);
      xh[10+8*i+4] = bf_lo(v.z); xh[10+8*i+5] = bf_hi(v.z);
      xh[10+8*i+6] = bf_lo(v.w); xh[10+8*i+7] = bf_hi(v.w);
    }
  }

  // Phase A: r-gate only -> rh[32] = sigmoid(a_r) * h   (z deferred to phase B)
  float rh[HIDF];
  #pragma unroll
  for (int j = 0; j < HIDF; j++){
    float ar = br[j];
    const float* wr = Wr + j * DIN;
    #pragma unroll
    for (int k = 0; k < DIN; k++) ar = fmaf(xh[k], wr[k], ar);
    rh[j] = sigmoid_fast(ar) * xh[10 + j];
  }

  // Phase B: per-j z-gate, h_tilde, blend, head-accumulate.
  // z_j consumed immediately; h_new buffered 4-at-a-time (static indices
  // under full unroll -> stays in registers) and stored as float4.
  float o0 = bl[0], o1 = bl[1];
  float hc0, hc1, hc2, hc3;
  float4* oh = (float4*)(outh + (size_t)n * 32);
  #pragma unroll
  for (int j = 0; j < HIDF; j++){
    float az = bz[j];
    const float* wz = Wz + j * DIN;
    #pragma unroll
    for (int k = 0; k < DIN; k++) az = fmaf(xh[k], wz[k], az);

    float ah = bh[j];
    const float* wh = Wh + j * DIN;
    #pragma unroll
    for (int k = 0; k < 10; k++) ah = fmaf(xh[k], wh[k], ah);
    #pragma unroll
    for (int k = 0; k < 32; k++) ah = fmaf(rh[k], wh[10 + k], ah);

    float zj = sigmoid_fast(az);
    float ht = tanh_fast(ah);
    float hn = fmaf(zj, xh[10 + j] - ht, ht);     // z*h + (1-z)*ht

    float rl = fmaxf(hn, 0.0f);
    o0 = fmaf(rl, Wl[j],      o0);
    o1 = fmaf(rl, Wl[32 + j], o1);

    switch (j & 3) {
      case 0: hc0 = hn; break;
      case 1: hc1 = hn; break;
      case 2: hc2 = hn; break;
      default:
        hc3 = hn;
        oh[j >> 2] = make_float4(hc0, hc1, hc2, hc3);
        break;
    }
  }

  ((float2*)out0)[n] = make_float2(o0, o1);       // out[n][0..1], f32
}

extern "C" void kernel_launch(void* const* d_in, const int* in_sizes, int n_in,
                              void* d_out, int out_size, void* d_ws, size_t ws_size,
                              hipStream_t stream) {
  // setup_inputs order:
  // 0:x 1:edge_index(unused) 2:edge_weight(unused) 3:h
  // 4:W_z 5:b_z 6:W_r 7:b_r 8:W_h 9:b_h 10:W_lin 11:b_lin
  const uint32_t* x = (const uint32_t*)d_in[0];
  const uint32_t* h = (const uint32_t*)d_in[3];

  float* ws = (float*)d_ws;   // 16808 bytes used

  prep_kernel<<<6, 256, 0, stream>>>(d_in[4], d_in[5], d_in[6], d_in[7],
                                     d_in[8], d_in[9], d_in[10], d_in[11],
                                     x, h, ws);

  float* outf = (float*)d_out;
  float* out0 = outf;                              // out   [N,2]  f32
  float* outh = outf + (size_t)2 * N_NODES;        // h_new [N,32] f32
  dcrnn_kernel<<<(N_NODES + 255) / 256, 256, 0, stream>>>(
      x, h, ws, out0, outh);
}

// Round 3
// 272.187 us; speedup vs baseline: 1.1558x; 1.1558x over previous
//
#include <hip/hip_runtime.h>
#include <hip/hip_bf16.h>
#include <stdint.h>

// Problem constants (reference: N=500000, F_IN=10, HID=32, OUT=2, d_in=42)
// Settled world model (R0-R4 evidence):
//   ALL float tensors (x, h, weights, biases, outputs) are f32 on device.
//   The harness compares against a bf16-QUANTIZED np reference with a
//   bf16-floor threshold (0.088) — hence the "(bf16, ref=np)" label.
//   Outputs flat f32: out [N,2] at [0,1e6), h_new [N,32] at [1e6,17e6).
// Input dtype auto-detection retained (proven to resolve f32; guards drift).
//
// R6/R7 change (packed-f16 math + register-demand fix):
//   R5 evidence: VGPR_Count=60 despite launch_bounds(256,4)'s 128 budget ->
//   allocator chose occupancy and rematerialized/spilled the f32 working set
//   (xh[42]+rh[32] can't fit in 60 regs); VALUBusy 49% = 62us of issue vs
//   ~30us of real math; WRITE_SIZE 73->95MB from scattered partial-line
//   float4 stores. Fix:
//     * All dot products in packed f16 (v_pk_fma_f16): xh2[21] half2 regs,
//       rh2[16] half2 regs, f16 per-half-lane accum, f32 reduce at the end.
//       Halves dot-product VALU count AND halves register demand.
//     * Weight table packed f16: 16.5KB -> 8.4KB, fits the 16KB scalar K$
//       (the per-wave weight stream was thrashing it).
//     * asm("+v") pins on xh2/rh2 block rematerialization-from-global.
//     * h_new stores back to an end-of-kernel burst (fully covered lines).
//   R7: fix cvt_pkrtz return-type mismatch via __builtin_bit_cast (the
//   builtin returns a __fp16 vector; identical bits, no codegen change).
static constexpr int N_NODES = 500000;
static constexpr int DIN     = 42;    // F_IN + HID
static constexpr int HIDF    = 32;
static constexpr int NPAIR   = 21;    // DIN/2 packed half2 per row

typedef _Float16 f16x2 __attribute__((ext_vector_type(2)));

// d_ws u32/float layout (written by prep_kernel every launch), u32-indexed:
//   [0)     wz2[32][21]  packed half2 rows of combined W_z[0]+W_z[1], transposed
//   [672)   wr2[32][21]
//   [1344)  wh2[32][21]
//   [2016)  bz f32[32]   [2048) br f32[32]   [2080) bh f32[32]
//   [2112)  Wl f32[64]   [2176) bl f32[2]
//   [2180)  x_is_f32 flag   [2181) h_is_f32 flag

__device__ __forceinline__ float bfdec(uint32_t b){
  union{uint32_t u; float f;} c; c.u = b << 16; return c.f;
}
__device__ __forceinline__ float bf_lo(uint32_t u){ union{uint32_t u; float f;} c; c.u = u << 16; return c.f; }
__device__ __forceinline__ float bf_hi(uint32_t u){ union{uint32_t u; float f;} c; c.u = u & 0xffff0000u; return c.f; }
__device__ __forceinline__ float sigmoid_fast(float x){
  float e = __expf(-x);
  return __builtin_amdgcn_rcpf(1.0f + e);
}
__device__ __forceinline__ float tanh_fast(float x){
  float e = __expf(2.0f * x);
  return 1.0f - 2.0f * __builtin_amdgcn_rcpf(e + 1.0f);
}

__device__ __forceinline__ f16x2 pk2(float a, float b){
#if __has_builtin(__builtin_amdgcn_cvt_pkrtz)
  return __builtin_bit_cast(f16x2, __builtin_amdgcn_cvt_pkrtz(a, b));
#else
  f16x2 r; r[0] = (_Float16)a; r[1] = (_Float16)b; return r;
#endif
}

// bf16-packed data: lo u16 of each u32 decodes to a real value (|v| <~ 6).
// f32 data: lo u16 = random mantissa bits -> decoded bf16 exponent uniform
// 0..255 -> max over K samples explodes past 1e6 w.p. ~1.
__device__ bool detect_f32_words(const uint32_t* w, int K){
  float m = 0.0f;
  for (int i = 0; i < K; i++) m = fmaxf(m, fabsf(bfdec(w[i] & 0xffffu)));
  return !(m < 1e6f);   // NaN-safe: NaN => f32
}
__device__ __forceinline__ float wload(const void* p, int idx, bool f32w){
  if (f32w) return ((const float*)p)[idx];
  return bfdec(((const uint16_t*)p)[idx]);
}

__global__ void prep_kernel(const void* __restrict__ Wz,
                            const void* __restrict__ bz,
                            const void* __restrict__ Wr,
                            const void* __restrict__ br,
                            const void* __restrict__ Wh,
                            const void* __restrict__ bh,
                            const void* __restrict__ Wl,
                            const void* __restrict__ bl,
                            const uint32_t* __restrict__ xg,
                            const uint32_t* __restrict__ hg,
                            float* __restrict__ ws)
{
  const bool f32w = detect_f32_words((const uint32_t*)Wz, 64);
  uint32_t* wsu = (uint32_t*)ws;
  int i = blockIdx.x * 256 + threadIdx.x;
  if (i < 672) {
    // one packed half2 per (row j, pair p) for each of the 3 matrices.
    // combined+transposed: Wt[j][k] = W[0][k][j] + W[1][k][j]
    int j = i / NPAIR;
    int p = i - j * NPAIR;
    int k0 = 2 * p, k1 = 2 * p + 1;
    int s0 = k0 * HIDF + j;
    int s1 = k1 * HIDF + j;
    union { f16x2 h; uint32_t u; } cz, cr, ch;
    cz.h = pk2(wload(Wz, s0, f32w) + wload(Wz, 1344 + s0, f32w),
               wload(Wz, s1, f32w) + wload(Wz, 1344 + s1, f32w));
    cr.h = pk2(wload(Wr, s0, f32w) + wload(Wr, 1344 + s0, f32w),
               wload(Wr, s1, f32w) + wload(Wr, 1344 + s1, f32w));
    ch.h = pk2(wload(Wh, s0, f32w) + wload(Wh, 1344 + s0, f32w),
               wload(Wh, s1, f32w) + wload(Wh, 1344 + s1, f32w));
    wsu[i]         = cz.u;
    wsu[672 + i]   = cr.u;
    wsu[1344 + i]  = ch.u;
  } else if (i < 834) {
    int r = i - 672;
    if      (r < 32)  ws[2016 + r]        = wload(bz, r,       f32w);
    else if (r < 64)  ws[2048 + (r-32)]   = wload(br, r-32,    f32w);
    else if (r < 96)  ws[2080 + (r-64)]   = wload(bh, r-64,    f32w);
    else if (r < 160) ws[2112 + (r-96)]   = wload(Wl, r-96,    f32w);
    else              ws[2176 + (r-160)]  = wload(bl, r-160,   f32w);
  } else if (i == 900) {
    ws[2180] = detect_f32_words(xg, 256) ? 1.0f : 0.0f;
  } else if (i == 901) {
    ws[2181] = detect_f32_words(hg, 256) ? 1.0f : 0.0f;
  }
}

__global__ __launch_bounds__(256, 4) void dcrnn_kernel(
    const uint32_t* __restrict__ xg,    // x [N,10]: f32 (10 words/row) or bf16 (5 u32/row)
    const uint32_t* __restrict__ hg,    // h [N,32]: f32 (32 words/row) or bf16 (16 u32/row)
    const float*    __restrict__ ws,
    float* __restrict__ out0,           // f32 [N,2]   (d_out f32 offset 0)
    float* __restrict__ outh)           // f32 [N,32]  (d_out f32 offset 2N)
{
  const int n = blockIdx.x * 256 + threadIdx.x;
  if (n >= N_NODES) return;

  const uint32_t* wsu = (const uint32_t*)ws;
  const f16x2* wz2 = (const f16x2*)(wsu);
  const f16x2* wr2 = (const f16x2*)(wsu + 672);
  const f16x2* wh2 = (const f16x2*)(wsu + 1344);
  const float* bz = ws + 2016;
  const float* br = ws + 2048;
  const float* bh = ws + 2080;
  const float* Wl = ws + 2112;
  const float* bl = ws + 2176;
  const bool x_f32 = ws[2180] != 0.0f;   // wave-uniform scalar branch
  const bool h_f32 = ws[2181] != 0.0f;

  // xh packed: xh2[0..4] = x pairs, xh2[5..20] = h pairs
  f16x2 xh2[NPAIR];
  if (x_f32) {
    const float2* xr = (const float2*)((const float*)xg + (size_t)n * 10);
    #pragma unroll
    for (int i = 0; i < 5; i++){ float2 v = xr[i]; xh2[i] = pk2(v.x, v.y); }
  } else {
    const uint32_t* xr = xg + (size_t)n * 5;
    #pragma unroll
    for (int i = 0; i < 5; i++){ uint32_t u = xr[i]; xh2[i] = pk2(bf_lo(u), bf_hi(u)); }
  }
  if (h_f32) {
    const float4* hr = (const float4*)((const float*)hg + (size_t)n * 32);
    #pragma unroll
    for (int i = 0; i < 8; i++){
      float4 v = hr[i];
      xh2[5 + 2*i]     = pk2(v.x, v.y);
      xh2[5 + 2*i + 1] = pk2(v.z, v.w);
    }
  } else {
    const uint4* hr = (const uint4*)(hg + (size_t)n * 16);
    #pragma unroll
    for (int i = 0; i < 4; i++){
      uint4 v = hr[i];
      xh2[5 + 4*i]     = pk2(bf_lo(v.x), bf_hi(v.x));
      xh2[5 + 4*i + 1] = pk2(bf_lo(v.y), bf_hi(v.y));
      xh2[5 + 4*i + 2] = pk2(bf_lo(v.z), bf_hi(v.z));
      xh2[5 + 4*i + 3] = pk2(bf_lo(v.w), bf_hi(v.w));
    }
  }
  // Pin packed inputs in VGPRs: blocks rematerialization-from-global
  // (R5 evidence: compiler re-loaded h in phase B rather than keep regs).
  #pragma unroll
  for (int p = 0; p < NPAIR; p++) asm("" : "+v"(xh2[p]));

  // Phase A: r-gate, two rows at a time so rh packs directly into half2.
  f16x2 rh2[16];
  #pragma unroll
  for (int jj = 0; jj < 16; jj++){
    const int j0 = 2 * jj;
    const f16x2* r0 = wr2 + j0 * NPAIR;
    const f16x2* r1 = r0 + NPAIR;
    f16x2 a0 = {(_Float16)0.0f, (_Float16)0.0f};
    f16x2 a1 = {(_Float16)0.0f, (_Float16)0.0f};
    #pragma unroll
    for (int p = 0; p < NPAIR; p++){
      a0 = xh2[p] * r0[p] + a0;
      a1 = xh2[p] * r1[p] + a1;
    }
    float s0 = (float)a0[0] + (float)a0[1] + br[j0];
    float s1 = (float)a1[0] + (float)a1[1] + br[j0 + 1];
    float h0 = (float)xh2[5 + jj][0];
    float h1 = (float)xh2[5 + jj][1];
    rh2[jj] = pk2(sigmoid_fast(s0) * h0, sigmoid_fast(s1) * h1);
  }
  #pragma unroll
  for (int p = 0; p < 16; p++) asm("" : "+v"(rh2[p]));

  // Phase B: per-j z-gate + h_tilde + blend + head-accumulate.
  float o0 = bl[0], o1 = bl[1];
  float hnv[HIDF];
  #pragma unroll
  for (int j = 0; j < HIDF; j++){
    const f16x2* wzr = wz2 + j * NPAIR;
    const f16x2* whr = wh2 + j * NPAIR;
    f16x2 az = {(_Float16)0.0f, (_Float16)0.0f};
    f16x2 ah = {(_Float16)0.0f, (_Float16)0.0f};
    #pragma unroll
    for (int p = 0; p < NPAIR; p++) az = xh2[p] * wzr[p] + az;
    #pragma unroll
    for (int p = 0; p < 5; p++)     ah = xh2[p] * whr[p] + ah;
    #pragma unroll
    for (int p = 0; p < 16; p++)    ah = rh2[p] * whr[5 + p] + ah;

    float zs = (float)az[0] + (float)az[1] + bz[j];
    float hs = (float)ah[0] + (float)ah[1] + bh[j];
    float zj = sigmoid_fast(zs);
    float ht = tanh_fast(hs);
    float hj = (float)xh2[5 + (j >> 1)][j & 1];
    float hn = fmaf(zj, hj - ht, ht);             // z*h + (1-z)*ht
    hnv[j] = hn;

    float rl = fmaxf(hn, 0.0f);
    o0 = fmaf(rl, Wl[j],      o0);
    o1 = fmaf(rl, Wl[32 + j], o1);
  }

  ((float2*)out0)[n] = make_float2(o0, o1);       // out[n][0..1], f32

  // burst store: 8 back-to-back dwordx4 fully cover each lane's 128B row
  float4* oh = (float4*)(outh + (size_t)n * 32);
  #pragma unroll
  for (int i = 0; i < 8; i++)
    oh[i] = make_float4(hnv[4*i], hnv[4*i+1], hnv[4*i+2], hnv[4*i+3]);
}

extern "C" void kernel_launch(void* const* d_in, const int* in_sizes, int n_in,
                              void* d_out, int out_size, void* d_ws, size_t ws_size,
                              hipStream_t stream) {
  // setup_inputs order:
  // 0:x 1:edge_index(unused) 2:edge_weight(unused) 3:h
  // 4:W_z 5:b_z 6:W_r 7:b_r 8:W_h 9:b_h 10:W_lin 11:b_lin
  const uint32_t* x = (const uint32_t*)d_in[0];
  const uint32_t* h = (const uint32_t*)d_in[3];

  float* ws = (float*)d_ws;   // ~8.8 KB used

  prep_kernel<<<6, 256, 0, stream>>>(d_in[4], d_in[5], d_in[6], d_in[7],
                                     d_in[8], d_in[9], d_in[10], d_in[11],
                                     x, h, ws);

  float* outf = (float*)d_out;
  float* out0 = outf;                              // out   [N,2]  f32
  float* outh = outf + (size_t)2 * N_NODES;        // h_new [N,32] f32
  dcrnn_kernel<<<(N_NODES + 255) / 256, 256, 0, stream>>>(
      x, h, ws, out0, outh);
}

// Round 4
// 245.095 us; speedup vs baseline: 1.2835x; 1.1105x over previous
//
#include <hip/hip_runtime.h>
#include <stdint.h>

// Problem constants (reference: N=500000, F_IN=10, HID=32, OUT=2, d_in=42)
// Settled world model: all tensors f32 on device; harness threshold 0.088
// (bf16 floor). Outputs flat f32: out [N,2] at [0,1e6), h_new [N,32] after.
//
// R8: MFMA rewrite. Evidence: R0/R5/R7 all pinned at ~126us dispatch with
// VALUBusy 49/48/32%, occupancy 37/37/54%, HBM 11% -> latency-bound on the
// per-thread weight-load->FMA serial chains (issue demand ~42k cyc/SIMD vs
// 302k observed). Fix: the op is [N,42]@[42,96] -> use matrix cores.
//   * block = 256 nodes; xh staged bf16 [256][48] in LDS (stride 96B is
//     conflict-free for the 16x16x32 fragment read pattern); weights bf16
//     [96][48] (9KB) staged once per block.
//   * per wave (64 nodes, independent): GEMM1 -> z|r preacts (f32 accum),
//     sigmoid(r)*h written back into LDS cols 10..41 (bf16), GEMM2 -> h~,
//     blend, f32 stores; relu(h_new) bf16 back into the dead rh slots for
//     the per-thread head matvec.
//   * MFMA count: 48/wave vs ~2100 serial VALU FMAs/thread before.
// Fragment layouts (gfx950 16x16x32 bf16): A row=l&15, k=(l>>4)*8+i;
// B col=l&15, k=(l>>4)*8+i; C/D col=l&15, row=(l>>4)*4+q (HW-verified map).
static constexpr int N_NODES = 500000;

typedef __attribute__((ext_vector_type(8))) short short8;   // 8 bf16, 4 VGPRs
typedef __attribute__((ext_vector_type(4))) float f32x4;

// d_ws layout:
//   u16[0..4608): wzr bf16 [64 cols][48 k] (z cols 0-31, r cols 32-63),
//                 then wh bf16 [32][48] at u16 index 3072. k 42-47 zeroed.
//   f32 idx 2304: bz[32]  2336: br[32]  2368: bh[32]
//   f32 idx 2400: Wl[64]  2464: bl[2]   2466: x_f32 flag  2467: h_f32 flag

__device__ __forceinline__ float bfdec(uint32_t b){
  union{uint32_t u; float f;} c; c.u = b << 16; return c.f;
}
__device__ __forceinline__ uint32_t bfrne(float f){   // f32 -> bf16 (RNE)
  union{float f; uint32_t u;} c; c.f = f;
  return (c.u + 0x7fffu + ((c.u >> 16) & 1u)) >> 16;
}
__device__ __forceinline__ uint32_t pack2(float a, float b){
  return bfrne(a) | (bfrne(b) << 16);
}
__device__ __forceinline__ float sigmoid_fast(float x){
  float e = __expf(-x);
  return __builtin_amdgcn_rcpf(1.0f + e);
}
__device__ __forceinline__ float tanh_fast(float x){
  float e = __expf(2.0f * x);
  return 1.0f - 2.0f * __builtin_amdgcn_rcpf(e + 1.0f);
}

// bf16-packed data: lo u16 decodes to |v| <~ 6; f32 data: lo u16 is random
// mantissa bits -> decoded exponent uniform -> max explodes past 1e6 w.p.~1.
__device__ bool detect_f32_words(const uint32_t* w, int K){
  float m = 0.0f;
  for (int i = 0; i < K; i++) m = fmaxf(m, fabsf(bfdec(w[i] & 0xffffu)));
  return !(m < 1e6f);   // NaN-safe: NaN => f32
}
__device__ __forceinline__ float wload(const void* p, int idx, bool f32w){
  if (f32w) return ((const float*)p)[idx];
  return bfdec(((const uint16_t*)p)[idx]);
}

__global__ void prep_kernel(const void* __restrict__ Wz,
                            const void* __restrict__ bz,
                            const void* __restrict__ Wr,
                            const void* __restrict__ br,
                            const void* __restrict__ Wh,
                            const void* __restrict__ bh,
                            const void* __restrict__ Wl,
                            const void* __restrict__ bl,
                            const uint32_t* __restrict__ xg,
                            const uint32_t* __restrict__ hg,
                            float* __restrict__ ws)
{
  const bool f32w = detect_f32_words((const uint32_t*)Wz, 64);
  uint16_t* wsh = (uint16_t*)ws;
  float*    wsf = ws;
  int i = blockIdx.x * 256 + threadIdx.x;
  if (i < 4608) {
    // bf16 weight tables, transposed+combined: Wt[col][k] = W[0][k][col]+W[1][k][col]
    float v = 0.0f;
    if (i < 3072) {                 // wzr: col 0-31 = z, 32-63 = r
      int col = i / 48, k = i - col * 48;
      if (k < 42) {
        const void* Wp = (col < 32) ? Wz : Wr;
        int j = (col < 32) ? col : col - 32;
        int src = k * 32 + j;
        v = wload(Wp, src, f32w) + wload(Wp, 1344 + src, f32w);
      }
    } else {                        // wh
      int b2 = i - 3072;
      int col = b2 / 48, k = b2 - col * 48;
      if (k < 42) {
        int src = k * 32 + col;
        v = wload(Wh, src, f32w) + wload(Wh, 1344 + src, f32w);
      }
    }
    wsh[i] = (uint16_t)bfrne(v);
  } else if (i < 4608 + 162) {
    int r = i - 4608;
    if      (r < 32)  wsf[2304 + r]        = wload(bz, r,     f32w);
    else if (r < 64)  wsf[2336 + (r-32)]   = wload(br, r-32,  f32w);
    else if (r < 96)  wsf[2368 + (r-64)]   = wload(bh, r-64,  f32w);
    else if (r < 160) wsf[2400 + (r-96)]   = wload(Wl, r-96,  f32w);
    else              wsf[2464 + (r-160)]  = wload(bl, r-160, f32w);
  } else if (i == 4800) {
    wsf[2466] = detect_f32_words(xg, 256) ? 1.0f : 0.0f;
  } else if (i == 4801) {
    wsf[2467] = detect_f32_words(hg, 256) ? 1.0f : 0.0f;
  }
}

__global__ __launch_bounds__(256, 4) void dcrnn_kernel(
    const uint32_t* __restrict__ xg,    // x [N,10]: f32 or bf16-packed
    const uint32_t* __restrict__ hg,    // h [N,32]: f32 or bf16-packed
    const float*    __restrict__ ws,
    float* __restrict__ out0,           // f32 [N,2]
    float* __restrict__ outh)           // f32 [N,32]
{
  __shared__ __align__(16) uint16_t w_u16[4608];       //  9 KB weights
  __shared__ __align__(16) uint16_t xh_u16[256 * 48];  // 24 KB A-tile

  const int t  = threadIdx.x;
  const int nd = blockIdx.x * 256 + t;
  const bool valid = nd < N_NODES;
  const float* wsf = ws;
  const bool x_f32 = wsf[2466] != 0.0f;
  const bool h_f32 = wsf[2467] != 0.0f;

  // ---- stage weights (block-cooperative) ----
  const uint4* wsq = (const uint4*)ws;       // 9216 B = 576 uint4
  for (int i = t; i < 576; i += 256) ((uint4*)w_u16)[i] = wsq[i];

  // ---- stage this thread's node row: bf16 [48], cols 0-9 x, 10-41 h, 42-47 pad ----
  uint32_t rw[24];
  #pragma unroll
  for (int i = 0; i < 24; i++) rw[i] = 0u;
  if (valid) {
    if (x_f32) {
      const float2* xr = (const float2*)((const float*)xg + (size_t)nd * 10);
      #pragma unroll
      for (int i = 0; i < 5; i++){ float2 v = xr[i]; rw[i] = pack2(v.x, v.y); }
    } else {
      const uint32_t* xr = xg + (size_t)nd * 5;
      #pragma unroll
      for (int i = 0; i < 5; i++) rw[i] = xr[i];     // already 2×bf16 per u32
    }
    if (h_f32) {
      const float4* hr = (const float4*)((const float*)hg + (size_t)nd * 32);
      #pragma unroll
      for (int i = 0; i < 8; i++){
        float4 v = hr[i];
        rw[5 + 2*i]     = pack2(v.x, v.y);
        rw[5 + 2*i + 1] = pack2(v.z, v.w);
      }
    } else {
      const uint4* hr = (const uint4*)(hg + (size_t)nd * 16);
      #pragma unroll
      for (int i = 0; i < 4; i++){
        uint4 v = hr[i];
        rw[5 + 4*i]     = v.x; rw[5 + 4*i + 1] = v.y;
        rw[5 + 4*i + 2] = v.z; rw[5 + 4*i + 3] = v.w;
      }
    }
  }
  {
    uint4* dst = (uint4*)(xh_u16 + t * 48);
    #pragma unroll
    for (int c = 0; c < 6; c++)
      dst[c] = make_uint4(rw[4*c], rw[4*c+1], rw[4*c+2], rw[4*c+3]);
  }
  __syncthreads();

  // ---- per-wave MFMA pipeline: wave w owns rows [64w, 64w+64) ----
  const int l = t & 63, w = t >> 6;
  const int lo16 = l & 15, g = l >> 4;
  uint16_t* xwm = xh_u16 + (w * 64) * 48;

  const float bzc0 = wsf[2304 + lo16], bzc1 = wsf[2320 + lo16];
  const float brc0 = wsf[2336 + lo16], brc1 = wsf[2352 + lo16];
  const float bhc0 = wsf[2368 + lo16], bhc1 = wsf[2384 + lo16];

  const short8 zero8 = {0,0,0,0,0,0,0,0};

  #pragma unroll
  for (int mt = 0; mt < 4; mt++){
    const uint16_t* arow = xwm + (mt*16 + lo16) * 48;
    short8 a0 = *(const short8*)(arow + g*8);
    short8 a1 = zero8;
    if (g < 2) a1 = *(const short8*)(arow + 32 + g*8);

    // GEMM1: z (cols 0-31) and r (cols 32-63) preacts, bias in acc init
    f32x4 accZ0 = {bzc0,bzc0,bzc0,bzc0};
    f32x4 accZ1 = {bzc1,bzc1,bzc1,bzc1};
    f32x4 accR0 = {brc0,brc0,brc0,brc0};
    f32x4 accR1 = {brc1,brc1,brc1,brc1};
    #pragma unroll
    for (int nt = 0; nt < 4; nt++){
      const uint16_t* brow = w_u16 + (nt*16 + lo16) * 48;
      short8 b0 = *(const short8*)(brow + g*8);
      short8 b1 = zero8;
      if (g < 2) b1 = *(const short8*)(brow + 32 + g*8);
      f32x4 acc = (nt==0)?accZ0:(nt==1)?accZ1:(nt==2)?accR0:accR1;
      acc = __builtin_amdgcn_mfma_f32_16x16x32_bf16(a0, b0, acc, 0, 0, 0);
      acc = __builtin_amdgcn_mfma_f32_16x16x32_bf16(a1, b1, acc, 0, 0, 0);
      if (nt==0) accZ0 = acc; else if (nt==1) accZ1 = acc;
      else if (nt==2) accR0 = acc; else accR1 = acc;
    }

    // rh pass: save h (f32 from bf16), overwrite LDS cols 10-41 with r*h
    f32x4 hs0, hs1;
    #pragma unroll
    for (int q = 0; q < 4; q++){
      int row = mt*16 + g*4 + q;
      uint16_t* p0 = xwm + row*48 + 10 + lo16;
      uint16_t* p1 = xwm + row*48 + 26 + lo16;
      float h0 = bfdec(*p0), h1 = bfdec(*p1);
      float r0 = sigmoid_fast(accR0[q]);
      float r1 = sigmoid_fast(accR1[q]);
      *p0 = (uint16_t)bfrne(r0 * h0);
      *p1 = (uint16_t)bfrne(r1 * h1);
      hs0[q] = h0; hs1[q] = h1;
    }
    asm volatile("s_waitcnt lgkmcnt(0)" ::: "memory");  // cross-lane LDS RAW

    // GEMM2: h_tilde preacts from [x | r*h]
    f32x4 accH0 = {bhc0,bhc0,bhc0,bhc0};
    f32x4 accH1 = {bhc1,bhc1,bhc1,bhc1};
    short8 c0 = *(const short8*)(arow + g*8);
    short8 c1 = zero8;
    if (g < 2) c1 = *(const short8*)(arow + 32 + g*8);
    #pragma unroll
    for (int nt = 0; nt < 2; nt++){
      const uint16_t* brow = w_u16 + 3072 + (nt*16 + lo16) * 48;
      short8 b0 = *(const short8*)(brow + g*8);
      short8 b1 = zero8;
      if (g < 2) b1 = *(const short8*)(brow + 32 + g*8);
      f32x4 acc = (nt==0) ? accH0 : accH1;
      acc = __builtin_amdgcn_mfma_f32_16x16x32_bf16(c0, b0, acc, 0, 0, 0);
      acc = __builtin_amdgcn_mfma_f32_16x16x32_bf16(c1, b1, acc, 0, 0, 0);
      if (nt==0) accH0 = acc; else accH1 = acc;
    }

    // blend + store h_new (f32), stash relu(h_new) bf16 in dead rh slots
    #pragma unroll
    for (int q = 0; q < 4; q++){
      int row  = mt*16 + g*4 + q;
      int node = blockIdx.x*256 + w*64 + row;
      float z0 = sigmoid_fast(accZ0[q]);
      float z1 = sigmoid_fast(accZ1[q]);
      float t0 = tanh_fast(accH0[q]);
      float t1 = tanh_fast(accH1[q]);
      float hn0 = fmaf(z0, hs0[q] - t0, t0);
      float hn1 = fmaf(z1, hs1[q] - t1, t1);
      if (node < N_NODES){
        outh[(size_t)node*32 + lo16]      = hn0;
        outh[(size_t)node*32 + 16 + lo16] = hn1;
      }
      *(xwm + row*48 + 10 + lo16) = (uint16_t)bfrne(fmaxf(hn0, 0.0f));
      *(xwm + row*48 + 26 + lo16) = (uint16_t)bfrne(fmaxf(hn1, 0.0f));
    }
  }

  // ---- head: per-thread 32-MAC matvec from LDS relu values ----
  asm volatile("s_waitcnt lgkmcnt(0)" ::: "memory");
  if (valid){
    float o0 = wsf[2464], o1 = wsf[2465];
    const uint16_t* hr = xh_u16 + t*48 + 10;
    #pragma unroll
    for (int c = 0; c < 32; c++){
      float v = bfdec(hr[c]);
      o0 = fmaf(v, wsf[2400 + c], o0);
      o1 = fmaf(v, wsf[2432 + c], o1);
    }
    ((float2*)out0)[nd] = make_float2(o0, o1);
  }
}

extern "C" void kernel_launch(void* const* d_in, const int* in_sizes, int n_in,
                              void* d_out, int out_size, void* d_ws, size_t ws_size,
                              hipStream_t stream) {
  // setup_inputs order:
  // 0:x 1:edge_index(unused) 2:edge_weight(unused) 3:h
  // 4:W_z 5:b_z 6:W_r 7:b_r 8:W_h 9:b_h 10:W_lin 11:b_lin
  const uint32_t* x = (const uint32_t*)d_in[0];
  const uint32_t* h = (const uint32_t*)d_in[3];

  float* ws = (float*)d_ws;   // ~9.9 KB used

  prep_kernel<<<19, 256, 0, stream>>>(d_in[4], d_in[5], d_in[6], d_in[7],
                                      d_in[8], d_in[9], d_in[10], d_in[11],
                                      x, h, ws);

  float* outf = (float*)d_out;
  float* out0 = outf;                              // out   [N,2]  f32
  float* outh = outf + (size_t)2 * N_NODES;        // h_new [N,32] f32
  dcrnn_kernel<<<(N_NODES + 255) / 256, 256, 0, stream>>>(
      x, h, ws, out0, outh);
}